// Round 4
// baseline (16536.421 us; speedup 1.0000x reference)
//
#include <hip/hip_runtime.h>

// ManifoldRNN: B=64, S=2048, I=H=O=256, L=2.
// Plan:
//   1) prep:     swizzle w_h0,w_q,u_h0,w_h1,u_h1 (fp32) -> fp16
//                fragment-contiguous layout sw=(k>>3)*2048+n*8+(k&7) in ws
//   2) gemm256<A=fp32,C=fp16>: A0[b,t,:] = x@w_h0 + b_h0
//   3) rnn "fused8": 64 blocks (1/batch) x 512 thr (8 waves, 2/SIMD).
//      Lane = (col c, K-half kh). Each lane holds U0,W1,U1 columns for its
//      K-half = 48 named half8 = 192 VGPRs. Per step: ONE read of the h0-slice
//      feeds BOTH U0 and W1 dots (they consume the same vector h0n(tau-1)),
//      one read of the h1-slice feeds U1. K-half partials exchanged via LDS;
//      2 barriers/step. LDS broadcast reads/CU/step: 384 (old) -> 256+.
//   4) gemm256<A=fp16,C=fp32>: y = H1_all@w_q + b_q -> d_out
//
// R4 rationale: VGPR_Count pinned at 84 across R1-R3 regardless of
// launch_bounds/waves_per_eu/named-SSA => likely the ds_read prefetch window
// (up to 32 hoisted b128 = 128 VGPRs) on top of 128 weight VGPRs blew the 170
// budget and RA spilled the weights. Independently, 12 waves x 32 broadcast
// ds_read_b128 = 384 LDS instrs/CU/step ~ 1900+ cyc at the per-CU LDS pipe --
// possibly the real bottleneck. fused8 fixes both: 256-budget occupancy with
// 192-reg base + sched_group_barrier-capped read window (~32 regs), and 33%
// fewer LDS reads via the shared-h0 U0/W1 dot.
#define S_LEN 2048
#define NB    64
#define HD    256

typedef _Float16 half2_t  __attribute__((ext_vector_type(2)));
typedef _Float16 half8_t  __attribute__((ext_vector_type(8)));
typedef float    floatx4  __attribute__((ext_vector_type(4)));
typedef float    floatx8  __attribute__((ext_vector_type(8)));
typedef float    floatx16 __attribute__((ext_vector_type(16)));

__device__ __forceinline__ float fdot2(half2_t a, half2_t b, float c){
#if __has_builtin(__builtin_amdgcn_fdot2)
  return __builtin_amdgcn_fdot2(a, b, c, false);
#else
  return c + (float)a[0]*(float)b[0] + (float)a[1]*(float)b[1];
#endif
}

__device__ __forceinline__ float tanh_fast(float x){
  // tanh(x) = 1 - 2/(e^{2x}+1); |preact| <~ 10, saturates correctly.
  float e = __expf(2.0f * x);
  return 1.0f - 2.0f / (e + 1.0f);
}

#define SEL2(v,a,b) __builtin_shufflevector(v, v, a, b)
#define FOR16(M) M(0)M(1)M(2)M(3)M(4)M(5)M(6)M(7)M(8)M(9)M(10)M(11)M(12)M(13)M(14)M(15)

// 48 named half8 weight registers: U0, W1, U1 columns (K-half each).
#define DECLW(i) half8_t U0_##i, W1_##i, U1_##i;
#define LOADW(i) U0_##i = *(const half8_t*)(u0p + (i)*2048);                   \
                 W1_##i = *(const half8_t*)(w1p + (i)*2048);                   \
                 U1_##i = *(const half8_t*)(u1p + (i)*2048);

// Shared-read dot chunk: one broadcast c_ feeds U0 and W1 chains (2 acc each).
#define DOT01(i) { half8_t c_ = hv0[i];                                        \
    u0a = fdot2(SEL2(c_,0,1), SEL2(U0_##i,0,1), u0a);                          \
    u0b = fdot2(SEL2(c_,2,3), SEL2(U0_##i,2,3), u0b);                          \
    w1a = fdot2(SEL2(c_,0,1), SEL2(W1_##i,0,1), w1a);                          \
    w1b = fdot2(SEL2(c_,2,3), SEL2(W1_##i,2,3), w1b);                          \
    u0a = fdot2(SEL2(c_,4,5), SEL2(U0_##i,4,5), u0a);                          \
    u0b = fdot2(SEL2(c_,6,7), SEL2(U0_##i,6,7), u0b);                          \
    w1a = fdot2(SEL2(c_,4,5), SEL2(W1_##i,4,5), w1a);                          \
    w1b = fdot2(SEL2(c_,6,7), SEL2(W1_##i,6,7), w1b); }

// U1 dot chunk: 4 acc chains (dep distance 4 instrs >= fdot2 latency).
#define DOTU1(i) { half8_t c_ = hv1[i];                                        \
    x1a = fdot2(SEL2(c_,0,1), SEL2(U1_##i,0,1), x1a);                          \
    x1b = fdot2(SEL2(c_,2,3), SEL2(U1_##i,2,3), x1b);                          \
    x1c = fdot2(SEL2(c_,4,5), SEL2(U1_##i,4,5), x1c);                          \
    x1d = fdot2(SEL2(c_,6,7), SEL2(U1_##i,6,7), x1d); }

// ---------------------------------------------------------------------------
// fused8 persistent recurrence: one block per batch, 512 threads.
// lane: c = tid&255 (output col), kh = tid>>8 (K-half).
// step tau: all lanes compute partial dots U0p,W1p (from h0n(tau-1) slice,
// SHARED read) and U1p (from h1(tau-2) slice). Exchange partials via LDS.
// kh0 finalizes h0n(tau) (reads A0); kh1 finalizes h1n(tau-1) (writes H1).
// ---------------------------------------------------------------------------
__attribute__((amdgpu_flat_work_group_size(512, 512)))
__attribute__((amdgpu_waves_per_eu(2, 2)))
__global__ void rnn_kernel(const _Float16* __restrict__ A0,
                           const _Float16* __restrict__ u0sw,
                           const _Float16* __restrict__ w1sw,
                           const _Float16* __restrict__ u1sw,
                           const float* __restrict__ b_h1,
                           _Float16* __restrict__ H1,
                           float* __restrict__ hfinal)
{
  const int b   = blockIdx.x;
  const int tid = threadIdx.x;
  const int c   = tid & 255;
  const int kh  = tid >> 8;

  __shared__ __align__(16) _Float16 h0buf[2][HD];
  __shared__ __align__(16) _Float16 h1buf[2][HD];
  __shared__ __align__(16) float pU0x[HD];   // written by kh1, read by kh0
  __shared__ __align__(16) float pW1x[HD];   // written by kh0, read by kh1
  __shared__ __align__(16) float pU1x[HD];   // written by kh0, read by kh1

  if (tid < HD){
    h0buf[0][tid] = (_Float16)0.f; h0buf[1][tid] = (_Float16)0.f;
    h1buf[0][tid] = (_Float16)0.f; h1buf[1][tid] = (_Float16)0.f;
  }

  // Weight columns (fp16, pre-swizzled): lane's K-half = 16 chunks of 16B at
  // stride 4KB starting at kh*32768 + c*8 halfs. 48 named half8 = 192 VGPRs.
  const _Float16* u0p = u0sw + kh * 32768 + c * 8;
  const _Float16* w1p = w1sw + kh * 32768 + c * 8;
  const _Float16* u1p = u1sw + kh * 32768 + c * 8;
  FOR16(DECLW)
  FOR16(LOADW)

  const size_t base = (size_t)b * S_LEN * HD;
  const float bias = b_h1[c];                 // b_h0 folded into A0

  _Float16 a0p0 = (_Float16)0.f, a0p1 = (_Float16)0.f;  // depth-2 A0 prefetch
  if (kh == 0){
    a0p0 = A0[base + 0 * HD + c];
    a0p1 = A0[base + 1 * HD + c];
  }

  __syncthreads();

  for (int tau = 0; tau <= S_LEN; ++tau){
    // h0n(tau-1) slice: buffer (tau-1)&1 == (tau+1)&1. h1(tau-2): buffer tau&1.
    const half8_t* hv0 = (const half8_t*)(&h0buf[(tau + 1) & 1][0]) + kh * 16;
    const half8_t* hv1 = (const half8_t*)(&h1buf[tau & 1][0])       + kh * 16;

    float u0a=0.f,u0b=0.f,w1a=0.f,w1b=0.f,x1a=0.f,x1b=0.f,x1c=0.f,x1d=0.f;
    FOR16(DOT01)
    FOR16(DOTU1)

    // Scheduler guidance for this region: 8 ds_reads up front, then 1 read per
    // 8 VALU. Caps the live c_ window (~32 VGPRs) so base(192)+window stays
    // under the 256 budget -> no weight spill; read-to-use distance ~128 cyc
    // covers LDS latency.
    #pragma unroll
    for (int g_ = 0; g_ < 8; ++g_)
      __builtin_amdgcn_sched_group_barrier(0x100, 1, 0);          // DS_READ
    #pragma unroll
    for (int g_ = 0; g_ < 24; ++g_){
      __builtin_amdgcn_sched_group_barrier(0x002, 8, 0);          // VALU x8
      __builtin_amdgcn_sched_group_barrier(0x100, 1, 0);          // DS_READ
    }
    __builtin_amdgcn_sched_group_barrier(0x002, 16, 0);           // tail VALU

    if (kh){ pU0x[c] = u0a + u0b; }
    else   { pW1x[c] = w1a + w1b; pU1x[c] = x1a + x1b + x1c + x1d; }

    __syncthreads();   // partials published

    if (!kh){
      if (tau < S_LEN){
        float h = tanh_fast((u0a + u0b) + pU0x[c] + (float)a0p0);
        h0buf[tau & 1][c] = (_Float16)h;
        if (tau == S_LEN - 1) hfinal[(b << 9) + c] = h;
        a0p0 = a0p1;
        if (tau + 2 < S_LEN) a0p1 = A0[base + (size_t)(tau + 2) * HD + c];
      }
    } else {
      if (tau >= 1){
        const int t = tau - 1;
        float h = tanh_fast((w1a + w1b) + pW1x[c] +
                            (x1a + x1b + x1c + x1d) + pU1x[c] + bias);
        h1buf[t & 1][c] = (_Float16)h;
        H1[base + (size_t)t * HD + c] = (_Float16)h;
        if (t == S_LEN - 1) hfinal[(b << 9) + HD + c] = h;
      }
    }
    __syncthreads();   // state published for next step
  }
}

// ---------------------------------------------------------------------------
// Swizzle 5 matrices (fp32 [256,256] row-major) into fp16 fragment-contiguous
// layout: sw = (k>>3)*2048 + n*8 + (k&7). Used as MFMA B-frags by the GEMMs
// and as per-lane weight columns by the rnn kernel.
// ---------------------------------------------------------------------------
__global__ void prep_kernel(const float* __restrict__ w0, const float* __restrict__ wq,
                            const float* __restrict__ u0, const float* __restrict__ w1,
                            const float* __restrict__ u1,
                            _Float16* __restrict__ B0, _Float16* __restrict__ Bq,
                            _Float16* __restrict__ U0, _Float16* __restrict__ W1,
                            _Float16* __restrict__ U1)
{
  int i = blockIdx.x * 256 + threadIdx.x;
  for (int idx = i; idx < 65536; idx += 64 * 256){
    int k = idx >> 8, n = idx & 255;
    int sw = (k >> 3) * 2048 + n * 8 + (k & 7);
    B0[sw] = (_Float16)w0[idx];
    Bq[sw] = (_Float16)wq[idx];
    U0[sw] = (_Float16)u0[idx];
    W1[sw] = (_Float16)w1[idx];
    U1[sw] = (_Float16)u1[idx];
  }
}

// ---------------------------------------------------------------------------
// C[131072,256] = A[131072,256] @ B[256,256] + bias, fp16 MFMA 32x32x16.
// 512 blocks x 512 thr; each wave owns a 32-row x 256-col strip (8 col-tiles,
// 128 acc VGPRs). A-frags direct from global; B-frags from pre-swizzled global
// fp16 (L2-resident), perfectly coalesced. No LDS.
// ---------------------------------------------------------------------------
template<bool A_FP32, bool C_FP16>
__launch_bounds__(512)
__global__ void gemm256(const void* __restrict__ Ap,
                        const _Float16* __restrict__ Bsw,
                        const float* __restrict__ bias,
                        void* __restrict__ Cp)
{
  const int wave = threadIdx.x >> 6;
  const int lane = threadIdx.x & 63;
  const int r  = lane & 31;     // A row / B col / C col within tile
  const int hf = lane >> 5;     // k-half selector
  const size_t rowt = (size_t)blockIdx.x * 256 + (size_t)wave * 32;

  floatx16 acc[8];
  #pragma unroll
  for (int i = 0; i < 8; ++i)
    #pragma unroll
    for (int j = 0; j < 16; ++j) acc[i][j] = 0.f;

  const size_t arow = rowt + (size_t)r;
  #pragma unroll
  for (int ks = 0; ks < 16; ++ks){
    half8_t af;
    if (A_FP32){
      const float* A = (const float*)Ap;
      const floatx4* p = (const floatx4*)(A + arow * 256 + ks * 16 + hf * 8);
      floatx4 v0 = p[0], v1 = p[1];
      floatx8 v = __builtin_shufflevector(v0, v1, 0, 1, 2, 3, 4, 5, 6, 7);
      af = __builtin_convertvector(v, half8_t);
    } else {
      const _Float16* A = (const _Float16*)Ap;
      af = *(const half8_t*)(A + arow * 256 + ks * 16 + hf * 8);
    }
    #pragma unroll
    for (int ct = 0; ct < 8; ++ct){
      half8_t bf = *(const half8_t*)(Bsw + (size_t)(ks * 2 + hf) * 2048 + (ct * 32 + r) * 8);
      acc[ct] = __builtin_amdgcn_mfma_f32_32x32x16_f16(af, bf, acc[ct], 0, 0, 0);
    }
  }

  #pragma unroll
  for (int ct = 0; ct < 8; ++ct){
    const int col = ct * 32 + r;
    const float bc = bias[col];
    #pragma unroll
    for (int reg = 0; reg < 16; ++reg){
      const int rl = (reg & 3) + 8 * (reg >> 2) + 4 * hf;   // verified 32x32 C/D map
      const size_t idx = (rowt + rl) * 256 + col;
      float v = acc[ct][reg] + bc;
      if (C_FP16) ((_Float16*)Cp)[idx] = (_Float16)v;
      else        ((float*)Cp)[idx]    = v;
    }
  }
}

extern "C" void kernel_launch(void* const* d_in, const int* in_sizes, int n_in,
                              void* d_out, int out_size, void* d_ws, size_t ws_size,
                              hipStream_t stream)
{
  (void)in_sizes; (void)n_in; (void)out_size;

  const float* x    = (const float*)d_in[0];
  const float* w_h0 = (const float*)d_in[1];
  const float* u_h0 = (const float*)d_in[2];
  const float* b_h0 = (const float*)d_in[3];
  const float* w_h1 = (const float*)d_in[4];
  const float* u_h1 = (const float*)d_in[5];
  const float* b_h1 = (const float*)d_in[6];
  const float* w_q  = (const float*)d_in[7];
  const float* b_q  = (const float*)d_in[8];

  const size_t MSH = (size_t)NB * S_LEN * HD;          // 33,554,432 elements
  float* y    = (float*)d_out;                         // [B,S,O] fp32
  float* hfin = y + MSH;                               // [B,2,H] fp32

  // Scratch layout. H1 always in ws. A0 in ws if it fits, else in d_out's low
  // half (A0 fully consumed by rnn before the Y-GEMM overwrites d_out).
  // 5 swizzled fp16 weight images (128KB each) follow.
  _Float16* H1 = (_Float16*)d_ws;
  _Float16 *A0, *B0sw, *Bqsw, *U0sw, *W1sw, *U1sw;
  if (ws_size >= (MSH * 2 + 5 * 65536) * sizeof(_Float16)){
    A0   = H1 + MSH;
    B0sw = A0 + MSH;
  } else {
    A0   = (_Float16*)d_out;    // 67MB fp16 in the 134MB output buffer
    B0sw = H1 + MSH;
  }
  Bqsw = B0sw + 65536;
  U0sw = Bqsw + 65536;
  W1sw = U0sw + 65536;
  U1sw = W1sw + 65536;

  prep_kernel<<<dim3(64), dim3(256), 0, stream>>>(w_h0, w_q, u_h0, w_h1, u_h1,
                                                  B0sw, Bqsw, U0sw, W1sw, U1sw);
  gemm256<true, true><<<dim3(512), dim3(512), 0, stream>>>((const void*)x, B0sw, b_h0, (void*)A0);
  rnn_kernel<<<dim3(NB), dim3(512), 0, stream>>>(A0, U0sw, W1sw, U1sw, b_h1, H1, hfin);
  gemm256<false, false><<<dim3(512), dim3(512), 0, stream>>>((const void*)H1, Bqsw, b_q, (void*)y);
}

// Round 5
// 3237.171 us; speedup vs baseline: 5.1083x; 5.1083x over previous
//
#include <hip/hip_runtime.h>

// ManifoldRNN: B=64, S=2048, I=H=O=256, L=2.
// R5 structure: split the two recurrences and move the cross-layer term into
// an MFMA GEMM (it needs no recurrence once H0 is materialized):
//   1) prep:  swizzle w_h0,w_q,u_h0,w_h1,u_h1 (fp32) -> fp16, sw=(k>>3)*2048+n*8+(k&7)
//   2) gemm:  A0 = x@w_h0 + b_h0                  (fp16)
//   3) rnn1:  h0(t)=tanh(A0(t)+h0(t-1)@u_h0)      -> H0 (fp16), hfinal[:,0,:]
//   4) gemm:  A1 = H0@w_h1 + b_h1                 (fp16)  [was a per-step matvec]
//   5) rnn2:  h1(t)=tanh(A1(t)+h1(t-1)@u_h1)      -> H1 (fp16), hfinal[:,1,:]
//   6) gemm:  y  = H1@w_q + b_q                   (fp32)
//
// rnn_layer: 64 blocks (1/batch) x 512 thr (8 waves). Wave w owns cols
// w*32..w*32+31; lane = (c, kh) with kh = lane>>5 (K-half WITHIN the wave).
// Per-lane weights = half a column = 16 named half8 = 64 VGPRs — fits under
// every allocator cap observed in R0-R4 (84/128), so no spill risk. K-half
// partials combine with one __shfl_xor(s,32); h state double-buffered in LDS;
// ONE __syncthreads per step; no sched_group_barriers (R4's forced schedule
// collapsed to 2.5% VALUBusy).
#define S_LEN 2048
#define NB    64
#define HD    256

typedef _Float16 half2_t  __attribute__((ext_vector_type(2)));
typedef _Float16 half8_t  __attribute__((ext_vector_type(8)));
typedef float    floatx4  __attribute__((ext_vector_type(4)));
typedef float    floatx8  __attribute__((ext_vector_type(8)));
typedef float    floatx16 __attribute__((ext_vector_type(16)));

__device__ __forceinline__ float fdot2(half2_t a, half2_t b, float c){
#if __has_builtin(__builtin_amdgcn_fdot2)
  return __builtin_amdgcn_fdot2(a, b, c, false);
#else
  return c + (float)a[0]*(float)b[0] + (float)a[1]*(float)b[1];
#endif
}

__device__ __forceinline__ float tanh_fast(float x){
  // tanh(x) = 1 - 2/(e^{2x}+1); |preact| <~ 10, saturates correctly.
  float e = __expf(2.0f * x);
  return 1.0f - 2.0f / (e + 1.0f);
}

#define SEL2(v,a,b) __builtin_shufflevector(v, v, a, b)
#define FOR16(M) M(0)M(1)M(2)M(3)M(4)M(5)M(6)M(7)M(8)M(9)M(10)M(11)M(12)M(13)M(14)M(15)

#define DECLW(i) half8_t W##i;
#define LOADW(i) W##i = *(const half8_t*)(up + (i)*2048);

// 8-elem K-chunk: broadcast h chunk c_ (2 distinct addrs per wave: one per
// K-half group) against named weight register. 4 accumulator chains.
#define DOTC(i) { half8_t c_ = hv[i];                                          \
    a0 = fdot2(SEL2(c_,0,1), SEL2(W##i,0,1), a0);                              \
    a1 = fdot2(SEL2(c_,2,3), SEL2(W##i,2,3), a1);                              \
    a2 = fdot2(SEL2(c_,4,5), SEL2(W##i,4,5), a2);                              \
    a3 = fdot2(SEL2(c_,6,7), SEL2(W##i,6,7), a3); }

// ---------------------------------------------------------------------------
// One-layer recurrence: h(t) = tanh(A(t) + h(t-1) @ U).  A has bias folded.
// ---------------------------------------------------------------------------
__attribute__((amdgpu_flat_work_group_size(512, 512)))
__attribute__((amdgpu_waves_per_eu(2, 2)))
__global__ void rnn_layer(const _Float16* __restrict__ A,     // [B,S,HD] fp16
                          const _Float16* __restrict__ Usw,   // swizzled fp16
                          _Float16* __restrict__ Hout,        // [B,S,HD] fp16
                          float* __restrict__ hfin_layer)     // hfin + layer*HD
{
  const int b    = blockIdx.x;
  const int tid  = threadIdx.x;
  const int wave = tid >> 6;
  const int lane = tid & 63;
  const int c    = (wave << 5) | (lane & 31);   // output col 0..255
  const int kh   = lane >> 5;                   // K-half within wave

  __shared__ __align__(16) _Float16 hbuf[2][HD];
  if (tid < HD){ hbuf[0][tid] = (_Float16)0.f; hbuf[1][tid] = (_Float16)0.f; }

  // 16 named half8 = 64 VGPRs: U[kh*128 .. kh*128+127][c], 8 k's per chunk.
  // sw layout => chunk i at up + i*2048, contiguous 16B, coalesced over lanes.
  const _Float16* up = Usw + (size_t)(kh * 16) * 2048 + c * 8;
  FOR16(DECLW)
  FOR16(LOADW)

  const size_t base = (size_t)b * S_LEN * HD;

  _Float16 ap0 = A[base + 0 * HD + c];          // depth-2 A prefetch
  _Float16 ap1 = A[base + 1 * HD + c];

  __syncthreads();

  for (int t = 0; t < S_LEN; ++t){
    const half8_t* hv = (const half8_t*)(&hbuf[t & 1][kh * 128]);

    float a0=0.f, a1=0.f, a2=0.f, a3=0.f;
    FOR16(DOTC)
    float s = (a0 + a1) + (a2 + a3);            // partial over this K-half
    s += __shfl_xor(s, 32);                     // full dot, both halves hold it

    float h = tanh_fast(s + (float)ap0);
    _Float16 hh = (_Float16)h;
    if (kh == 0){
      hbuf[(t + 1) & 1][c] = hh;                // publish state for t+1
      if (t == S_LEN - 1) hfin_layer[(b << 9) + c] = h;
    } else {
      Hout[base + (size_t)t * HD + c] = hh;     // stream H to global
    }

    ap0 = ap1;
    if (t + 2 < S_LEN) ap1 = A[base + (size_t)(t + 2) * HD + c];

    __syncthreads();
  }
}

// ---------------------------------------------------------------------------
// Swizzle 5 matrices (fp32 [256,256] row-major) into fp16 fragment-contiguous
// layout: sw = (k>>3)*2048 + n*8 + (k&7). Used as MFMA B-frags by the GEMMs
// and as per-lane weight columns by the rnn kernels.
// ---------------------------------------------------------------------------
__global__ void prep_kernel(const float* __restrict__ w0, const float* __restrict__ wq,
                            const float* __restrict__ u0, const float* __restrict__ w1,
                            const float* __restrict__ u1,
                            _Float16* __restrict__ B0, _Float16* __restrict__ Bq,
                            _Float16* __restrict__ U0, _Float16* __restrict__ W1,
                            _Float16* __restrict__ U1)
{
  int i = blockIdx.x * 256 + threadIdx.x;
  for (int idx = i; idx < 65536; idx += 64 * 256){
    int k = idx >> 8, n = idx & 255;
    int sw = (k >> 3) * 2048 + n * 8 + (k & 7);
    B0[sw] = (_Float16)w0[idx];
    Bq[sw] = (_Float16)wq[idx];
    U0[sw] = (_Float16)u0[idx];
    W1[sw] = (_Float16)w1[idx];
    U1[sw] = (_Float16)u1[idx];
  }
}

// ---------------------------------------------------------------------------
// C[131072,256] = A[131072,256] @ B[256,256] + bias, fp16 MFMA 32x32x16.
// 512 blocks x 512 thr; each wave owns a 32-row x 256-col strip (8 col-tiles,
// 128 acc VGPRs). A-frags direct from global; B-frags from pre-swizzled global
// fp16 (L2-resident), perfectly coalesced. No LDS.
// ---------------------------------------------------------------------------
template<bool A_FP32, bool C_FP16>
__launch_bounds__(512)
__global__ void gemm256(const void* __restrict__ Ap,
                        const _Float16* __restrict__ Bsw,
                        const float* __restrict__ bias,
                        void* __restrict__ Cp)
{
  const int wave = threadIdx.x >> 6;
  const int lane = threadIdx.x & 63;
  const int r  = lane & 31;     // A row / B col / C col within tile
  const int hf = lane >> 5;     // k-half selector
  const size_t rowt = (size_t)blockIdx.x * 256 + (size_t)wave * 32;

  floatx16 acc[8];
  #pragma unroll
  for (int i = 0; i < 8; ++i)
    #pragma unroll
    for (int j = 0; j < 16; ++j) acc[i][j] = 0.f;

  const size_t arow = rowt + (size_t)r;
  #pragma unroll
  for (int ks = 0; ks < 16; ++ks){
    half8_t af;
    if (A_FP32){
      const float* A = (const float*)Ap;
      const floatx4* p = (const floatx4*)(A + arow * 256 + ks * 16 + hf * 8);
      floatx4 v0 = p[0], v1 = p[1];
      floatx8 v = __builtin_shufflevector(v0, v1, 0, 1, 2, 3, 4, 5, 6, 7);
      af = __builtin_convertvector(v, half8_t);
    } else {
      const _Float16* A = (const _Float16*)Ap;
      af = *(const half8_t*)(A + arow * 256 + ks * 16 + hf * 8);
    }
    #pragma unroll
    for (int ct = 0; ct < 8; ++ct){
      half8_t bf = *(const half8_t*)(Bsw + (size_t)(ks * 2 + hf) * 2048 + (ct * 32 + r) * 8);
      acc[ct] = __builtin_amdgcn_mfma_f32_32x32x16_f16(af, bf, acc[ct], 0, 0, 0);
    }
  }

  #pragma unroll
  for (int ct = 0; ct < 8; ++ct){
    const int col = ct * 32 + r;
    const float bc = bias[col];
    #pragma unroll
    for (int reg = 0; reg < 16; ++reg){
      const int rl = (reg & 3) + 8 * (reg >> 2) + 4 * hf;   // verified 32x32 C/D map
      const size_t idx = (rowt + rl) * 256 + col;
      float v = acc[ct][reg] + bc;
      if (C_FP16) ((_Float16*)Cp)[idx] = (_Float16)v;
      else        ((float*)Cp)[idx]    = v;
    }
  }
}

extern "C" void kernel_launch(void* const* d_in, const int* in_sizes, int n_in,
                              void* d_out, int out_size, void* d_ws, size_t ws_size,
                              hipStream_t stream)
{
  (void)in_sizes; (void)n_in; (void)out_size;

  const float* x    = (const float*)d_in[0];
  const float* w_h0 = (const float*)d_in[1];
  const float* u_h0 = (const float*)d_in[2];
  const float* b_h0 = (const float*)d_in[3];
  const float* w_h1 = (const float*)d_in[4];
  const float* u_h1 = (const float*)d_in[5];
  const float* b_h1 = (const float*)d_in[6];
  const float* w_q  = (const float*)d_in[7];
  const float* b_q  = (const float*)d_in[8];

  const size_t MSH = (size_t)NB * S_LEN * HD;          // 33,554,432 elements
  float* y    = (float*)d_out;                         // [B,S,O] fp32
  float* hfin = y + MSH;                               // [B,2,H] fp32

  // Buffer plan (fp16, MSH elements each), lifetimes strictly serialized:
  //   bufA: A0 (made by gemm, eaten by rnn1) then A1 (made by gemm, eaten by rnn2)
  //   bufH: H0 (made by rnn1, eaten by A1-gemm) then H1 (made by rnn2, eaten by y-gemm)
  // bufH must NOT alias d_out (y-gemm reads it while writing y). bufA may live
  // in d_out's low 67MB: A1 is fully consumed by rnn2 before the y-gemm runs.
  _Float16* bufH = (_Float16*)d_ws;
  _Float16 *bufA, *B0sw;
  if (ws_size >= (MSH * 2 + 5 * 65536) * sizeof(_Float16)){
    bufA = bufH + MSH;
    B0sw = bufA + MSH;
  } else {
    bufA = (_Float16*)d_out;
    B0sw = bufH + MSH;
  }
  _Float16* Bqsw = B0sw + 65536;
  _Float16* U0sw = Bqsw + 65536;
  _Float16* W1sw = U0sw + 65536;
  _Float16* U1sw = W1sw + 65536;

  prep_kernel<<<dim3(64), dim3(256), 0, stream>>>(w_h0, w_q, u_h0, w_h1, u_h1,
                                                  B0sw, Bqsw, U0sw, W1sw, U1sw);
  // A0 = x @ w_h0 + b_h0
  gemm256<true, true><<<dim3(512), dim3(512), 0, stream>>>((const void*)x, B0sw, b_h0, (void*)bufA);
  // H0 = recur(A0; u_h0)
  rnn_layer<<<dim3(NB), dim3(512), 0, stream>>>(bufA, U0sw, bufH, hfin + 0);
  // A1 = H0 @ w_h1 + b_h1
  gemm256<false, true><<<dim3(512), dim3(512), 0, stream>>>((const void*)bufH, W1sw, b_h1, (void*)bufA);
  // H1 = recur(A1; u_h1)
  rnn_layer<<<dim3(NB), dim3(512), 0, stream>>>(bufA, U1sw, bufH, hfin + HD);
  // y = H1 @ w_q + b_q
  gemm256<false, false><<<dim3(512), dim3(512), 0, stream>>>((const void*)bufH, Bqsw, b_q, (void*)y);
}